// Round 17
// baseline (373.934 us; speedup 1.0000x reference)
//
#include <hip/hip_runtime.h>
#include <math.h>

#define NB 8
#define CIN 512
#define CM 32
#define MG 8
#define HH 128
#define WW 128
#define HWSZ (HH*WW)
#define EPSF 1e-5f
#define COT_ITAU 1.25f   // 1/0.8
#define LAM 0.7f
#define GFLOOR 0.05f

typedef float vf4 __attribute__((ext_vector_type(4)));
typedef short bf16x8 __attribute__((ext_vector_type(8)));
typedef float f32x4 __attribute__((ext_vector_type(4)));

__device__ __forceinline__ float wsum(float v){
#pragma unroll
  for (int o = 32; o; o >>= 1) v += __shfl_xor(v, o, 64);
  return v;
}

__device__ __forceinline__ unsigned short bfc(float x){
  unsigned u = __float_as_uint(x);
  return (unsigned short)((u + 0x7FFFu + ((u>>16)&1u)) >> 16);
}

// async 16B global -> LDS
__device__ __forceinline__ void gload16(const float* g, float* l){
  __builtin_amdgcn_global_load_lds(
    (const __attribute__((address_space(1))) void*)g,
    (__attribute__((address_space(3))) void*)l, 16, 0, 0);
}

// transpose compress weights [32][512] -> [512][32]; bf16-convert expand weights
__global__ void k_tw(const float* __restrict__ w, float* __restrict__ wT,
                     const float* __restrict__ ew, unsigned short* __restrict__ ewB){
  int i = blockIdx.x*256 + threadIdx.x;
  if (i < CM*CIN){
    int c = i >> 9, k = i & (CIN-1);
    wT[k*CM + c] = w[i];
    ewB[i] = bfc(ew[i]);
  }
}

// compress conv (512->32): 512-position blocks, 16-ch K-tiles -> 2KB bursts/row.
// 256 blocks x 512 thr (8 waves); gload_lds double-buffer; y position-major.
__global__ __launch_bounds__(512) void k_compress(
    const float* __restrict__ x, const float* __restrict__ wT,
    float* __restrict__ y2, float* __restrict__ s1, float* __restrict__ s2)
{
  __shared__ float lds[2][16][512];          // 64 KB
  int tid  = threadIdx.x;                    // 0..511
  int lane = tid & 63;
  int wv   = tid >> 6;                       // 0..7
  int blk  = blockIdx.x;                     // 0..255
  int b    = blk >> 5;
  int tile0 = (blk & 31) << 9;               // 512 positions
  const float* xb = x + ((size_t)b*CIN)*HWSZ + tile0;

  // stage K-tile t (16 channels x 512 pos): wave covers 2 rows, 2x 1KB back-to-back per row
#define STAGE(t, buf)                                                             \
  {                                                                               \
    _Pragma("unroll")                                                             \
    for (int j=0;j<2;j++){                                                        \
      int row = wv*2 + j;                                                         \
      gload16(xb + (size_t)((t)*16+row)*HWSZ +       lane*4, &lds[buf][row][0]);  \
      gload16(xb + (size_t)((t)*16+row)*HWSZ + 256 + lane*4, &lds[buf][row][256]);\
    }                                                                             \
  }

  STAGE(0, 0)
  __syncthreads();

  float acc[CM];
#pragma unroll
  for (int c=0;c<CM;c++) acc[c]=0.f;

  for (int t=0; t<32; ++t){
    int cur = t & 1;
    if (t+1 < 32) STAGE(t+1, cur^1)
    const float* wr0 = wT + (t*16)*CM;
#pragma unroll
    for (int i=0;i<16;i++){
      float xv = lds[cur][i][tid];
      const float* wr = wr0 + i*CM;          // uniform -> scalar loads
#pragma unroll
      for (int c=0;c<CM;c++) acc[c] = fmaf(wr[c], xv, acc[c]);
    }
    __syncthreads();
  }
#undef STAGE

  // stats
  {
    float ms=0.f, mq=0.f;
#pragma unroll
    for (int c=0;c<CM;c++){
      float s = wsum(acc[c]);
      float q = wsum(acc[c]*acc[c]);
      if ((lane)==c%64 && c<64){ }           // keep simple: below
      if (lane==c){ ms=s; mq=q; }
    }
    if (lane < CM){
      atomicAdd(&s1[b*CM+lane], ms);
      atomicAdd(&s2[b*CM+lane], mq);
    }
  }
  // position-major y write: thread owns position tile0+tid -> 8 contiguous vf4
  {
    vf4* yp = (vf4*)(y2 + ((size_t)b*HWSZ + tile0 + tid)*CM);
#pragma unroll
    for (int k=0;k<8;k++){
      vf4 v; v.x=acc[4*k]; v.y=acc[4*k+1]; v.z=acc[4*k+2]; v.w=acc[4*k+3];
      yp[k] = v;
    }
  }
}

// att_pre stats + BOTH pools; y read position-major (8 vf4/thread).
__global__ __launch_bounds__(256) void k_poolstat(
  const float* __restrict__ y2,
  const float* __restrict__ s1i, const float* __restrict__ s2i,
  const float* __restrict__ incg, const float* __restrict__ incb,
  const float* __restrict__ kw, const float* __restrict__ a1w,
  float* __restrict__ s1, float* __restrict__ s2,
  float* __restrict__ hpool, float* __restrict__ wpart)
{
  __shared__ float nA[CM], nB[CM];
  __shared__ float sh[CM][128];
  int tid=threadIdx.x;
  int blk=blockIdx.x;
  int b = blk >> 6;
  int p = ((blk&63)<<8)+tid;
  if (tid<CM){
    float mu  = s1i[b*CM+tid]*(1.f/HWSZ);
    float var = fmaf(-mu,mu, s2i[b*CM+tid]*(1.f/HWSZ));
    float a   = rsqrtf(var+EPSF)*incg[tid];
    nA[tid]=a; nB[tid]=incb[tid]-mu*a;
  }
  __syncthreads();
  float xc[CM], k1[CM], at[CM];
  {
    const vf4* yp = (const vf4*)(y2 + ((size_t)b*HWSZ + p)*CM);
#pragma unroll
    for (int k=0;k<8;k++){
      vf4 v = yp[k];
      xc[4*k]   = fmaxf(0.f, fmaf(v.x, nA[4*k],   nB[4*k]));
      xc[4*k+1] = fmaxf(0.f, fmaf(v.y, nA[4*k+1], nB[4*k+1]));
      xc[4*k+2] = fmaxf(0.f, fmaf(v.z, nA[4*k+2], nB[4*k+2]));
      xc[4*k+3] = fmaxf(0.f, fmaf(v.w, nA[4*k+3], nB[4*k+3]));
    }
  }
  if (tid>=128){
#pragma unroll
    for (int c=0;c<CM;c++) sh[c][tid-128]=xc[c];
  }
  __syncthreads();
  if (tid<128){
    float* wp = wpart + (size_t)blk*(CM*WW) + tid;
#pragma unroll
    for (int c=0;c<CM;c++) wp[c*WW] = xc[c] + sh[c][tid];
  }
  {
    int hrow = p >> 7;
    float ms=0.f;
#pragma unroll
    for (int c=0;c<CM;c++){
      float s=wsum(xc[c]);
      if ((tid&63)==c) ms=s;
    }
    int lane=tid&63;
    if (lane<CM) atomicAdd(&hpool[(b*CM+lane)*HH+hrow], ms*(1.f/WW));
  }
#pragma unroll
  for (int gI=0;gI<4;gI++)
#pragma unroll
    for (int o=0;o<MG;o++){
      float sk=0.f;
#pragma unroll
      for (int i=0;i<MG;i++) sk = fmaf(kw[gI*64+o*8+i], xc[gI*MG+i], sk);
      k1[gI*MG+o]=sk;
    }
#pragma unroll
  for (int gI=0;gI<4;gI++)
#pragma unroll
    for (int o=0;o<MG;o++){
      float s=0.f;
#pragma unroll
      for (int i=0;i<16;i++){
        float inp = (gI<2) ? k1[gI*16+i] : xc[(gI-2)*16+i];
        s = fmaf(a1w[gI*128+o*16+i], inp, s);
      }
      at[gI*MG+o]=s;
    }
  float ms=0.f,mq=0.f;
#pragma unroll
  for (int c=0;c<CM;c++){
    float s=wsum(at[c]); float q=wsum(at[c]*at[c]);
    if ((tid&63)==c){ms=s;mq=q;}
  }
  int lane=tid&63;
  if (lane<CM){ atomicAdd(&s1[b*CM+lane],ms); atomicAdd(&s2[b*CM+lane],mq); }
}

// reduce wpart -> wpool
__global__ void k_wred(const float* __restrict__ wpart, float* __restrict__ wpool){
  int bc = blockIdx.x;
  int w  = threadIdx.x;
  int b  = bc >> 5;
  int c  = bc & 31;
  const float* src = wpart + (size_t)(b*64)*(CM*WW) + c*WW + w;
  float s=0.f;
#pragma unroll 8
  for (int k=0;k<64;k++) s += src[(size_t)k*(CM*WW)];
  wpool[bc*WW + w] = s*(1.0f/HH);
}

// softmax denominator (y position-major); blocks 0..15 also run coord MLP
__global__ __launch_bounds__(256) void k_cot2(
  const float* __restrict__ y2,
  const float* __restrict__ s1i, const float* __restrict__ s2i,
  const float* __restrict__ incg, const float* __restrict__ incb,
  const float* __restrict__ s1a, const float* __restrict__ s2a,
  const float* __restrict__ ag, const float* __restrict__ ab,
  const float* __restrict__ kw, const float* __restrict__ a1w, const float* __restrict__ a2w,
  const float* __restrict__ hpool, const float* __restrict__ wpool,
  const float* __restrict__ pjw, const float* __restrict__ pjg, const float* __restrict__ pjb,
  const float* __restrict__ chw, const float* __restrict__ chb,
  const float* __restrict__ cww, const float* __restrict__ cwb,
  float* __restrict__ es, float* __restrict__ ah, float* __restrict__ aw)
{
  __shared__ float T[CM][HH+1];
  __shared__ float sa[CM], sb[CM], smx[CM], ssc[CM];
  __shared__ float nA[CM], nB[CM], tA[CM], tB[CM];
  int tid=threadIdx.x;
  int blk=blockIdx.x;
  int b = blk >> 6;
  int p = ((blk&63)<<8)+tid;
  if (tid<CM){
    float mu  = s1i[b*CM+tid]*(1.f/HWSZ);
    float var = fmaf(-mu,mu, s2i[b*CM+tid]*(1.f/HWSZ));
    float a   = rsqrtf(var+EPSF)*incg[tid];
    nA[tid]=a; nB[tid]=incb[tid]-mu*a;
    float mu2  = s1a[b*CM+tid]*(1.f/HWSZ);
    float var2 = fmaf(-mu2,mu2, s2a[b*CM+tid]*(1.f/HWSZ));
    float a2   = rsqrtf(var2+EPSF)*ag[tid];
    tA[tid]=a2; tB[tid]=ab[tid]-mu2*a2;
  }
  __syncthreads();
  float xc[CM], k1[CM], at[CM], l[CM];
  {
    const vf4* yp = (const vf4*)(y2 + ((size_t)b*HWSZ + p)*CM);
#pragma unroll
    for (int k=0;k<8;k++){
      vf4 v = yp[k];
      xc[4*k]   = fmaxf(0.f, fmaf(v.x, nA[4*k],   nB[4*k]));
      xc[4*k+1] = fmaxf(0.f, fmaf(v.y, nA[4*k+1], nB[4*k+1]));
      xc[4*k+2] = fmaxf(0.f, fmaf(v.z, nA[4*k+2], nB[4*k+2]));
      xc[4*k+3] = fmaxf(0.f, fmaf(v.w, nA[4*k+3], nB[4*k+3]));
    }
  }
#pragma unroll
  for (int gI=0;gI<4;gI++)
#pragma unroll
    for (int o=0;o<MG;o++){
      float sk=0.f;
#pragma unroll
      for (int i=0;i<MG;i++) sk = fmaf(kw[gI*64+o*8+i], xc[gI*MG+i], sk);
      k1[gI*MG+o]=sk;
    }
#pragma unroll
  for (int gI=0;gI<4;gI++)
#pragma unroll
    for (int o=0;o<MG;o++){
      float s=0.f;
#pragma unroll
      for (int i=0;i<16;i++){
        float inp = (gI<2) ? k1[gI*16+i] : xc[(gI-2)*16+i];
        s = fmaf(a1w[gI*128+o*16+i], inp, s);
      }
      at[gI*MG+o]=s;
    }
#pragma unroll
  for (int c=0;c<CM;c++)
    at[c] = fmaxf(0.f, fmaf(at[c], tA[c], tB[c]));
#pragma unroll
  for (int gI=0;gI<4;gI++)
#pragma unroll
    for (int o=0;o<MG;o++){
      float s=0.f;
#pragma unroll
      for (int i=0;i<MG;i++) s = fmaf(a2w[gI*64+o*8+i], at[gI*8+i], s);
      l[gI*MG+o]=s;
    }
  float ms=0.f;
#pragma unroll
  for (int c=0;c<CM;c++){
    float s = wsum(__expf(l[c]*COT_ITAU));
    if ((tid&63)==c) ms=s;
  }
  int lane=tid&63;
  if (lane<CM) atomicAdd(&es[b*CM+lane], ms);

  if (blk < 2*NB){
    int bb = blk>>1, path = blk&1;
    const float* pool = path ? wpool : hpool;
    const float* w2   = path ? cww : chw;
    const float* b2   = path ? cwb : chb;
    float* outp       = path ? aw  : ah;
    float z[CM];
    if (tid<HH){
      float in[CM];
#pragma unroll
      for (int c=0;c<CM;c++) in[c] = pool[(bb*CM+c)*HH + tid];
#pragma unroll
      for (int gI=0;gI<4;gI++)
#pragma unroll
        for (int o=0;o<MG;o++){
          float s=0.f;
#pragma unroll
          for (int i=0;i<MG;i++) s = fmaf(pjw[gI*64+o*8+i], in[gI*8+i], s);
          T[gI*8+o][tid] = s;
        }
    }
    __syncthreads();
    if (tid < CM){
      float s=0.f, q=0.f;
      for (int k=0;k<HH;k++){ float t=T[tid][k]; s+=t; q+=t*t; }
      float mu = s*(1.0f/HH);
      float var = q*(1.0f/HH) - mu*mu;
      float a = rsqrtf(var+EPSF)*pjg[tid];
      sa[tid]=a; sb[tid]=pjb[tid]-mu*a;
    }
    __syncthreads();
    if (tid<HH){
      float sil[CM];
#pragma unroll
      for (int c=0;c<CM;c++){
        float val = fmaf(T[c][tid], sa[c], sb[c]);
        sil[c] = val/(1.f+__expf(-val));
      }
#pragma unroll
      for (int gI=0;gI<4;gI++)
#pragma unroll
        for (int o=0;o<MG;o++){
          float s=b2[gI*8+o];
#pragma unroll
          for (int i=0;i<MG;i++) s = fmaf(w2[gI*64+o*8+i], sil[gI*8+i], s);
          z[gI*8+o]=s;
        }
    }
    __syncthreads();
    if (tid<HH){
#pragma unroll
      for (int c=0;c<CM;c++) T[c][tid]=z[c];
    }
    __syncthreads();
    if (tid < CM){
      float mx=-1e30f;
      for (int k=0;k<HH;k++) mx = fmaxf(mx, T[tid][k]);
      float s=0.f;
      for (int k=0;k<HH;k++) s += __expf(T[tid][k]-mx);
      smx[tid]=mx; ssc[tid]=(float)HH/s;
    }
    __syncthreads();
    if (tid<HH){
#pragma unroll
      for (int c=0;c<CM;c++)
        outp[(bb*CM+c)*HH + tid] = __expf(T[c][tid]-smx[c])*ssc[c];
    }
  }
}

// mix + cot_fuse + coord combine + fusion (+ fus stats); y/F position-major
__global__ __launch_bounds__(256) void k_mix_fuse(
  const float* __restrict__ y2,
  const float* __restrict__ s1i, const float* __restrict__ s2i,
  const float* __restrict__ incg, const float* __restrict__ incb,
  const float* __restrict__ s1a, const float* __restrict__ s2a,
  const float* __restrict__ ag, const float* __restrict__ ab,
  const float* __restrict__ kw, const float* __restrict__ vw,
  const float* __restrict__ a1w, const float* __restrict__ a2w,
  const float* __restrict__ ah, const float* __restrict__ awp, const float* __restrict__ es,
  const float* __restrict__ alpha, const float* __restrict__ beta,
  const float* __restrict__ fw, const float* __restrict__ fuw,
  float* __restrict__ F2, float* __restrict__ s1, float* __restrict__ s2)
{
  __shared__ float nA[CM], nB[CM], tA[CM], tB[CM];
  int tid=threadIdx.x;
  int b = blockIdx.x>>6;
  int p = ((blockIdx.x&63)<<8)+tid;
  int h = p >> 7, w = p & (WW-1);
  if (tid<CM){
    float mu  = s1i[b*CM+tid]*(1.f/HWSZ);
    float var = fmaf(-mu,mu, s2i[b*CM+tid]*(1.f/HWSZ));
    float a   = rsqrtf(var+EPSF)*incg[tid];
    nA[tid]=a; nB[tid]=incb[tid]-mu*a;
    float mu2  = s1a[b*CM+tid]*(1.f/HWSZ);
    float var2 = fmaf(-mu2,mu2, s2a[b*CM+tid]*(1.f/HWSZ));
    float a2   = rsqrtf(var2+EPSF)*ag[tid];
    tA[tid]=a2; tB[tid]=ab[tid]-mu2*a2;
  }
  __syncthreads();
  float al=alpha[0], be=beta[0];
  float xc[CM], k1[CM], at[CM], l[CM], t[CM];
  {
    const vf4* yp = (const vf4*)(y2 + ((size_t)b*HWSZ + p)*CM);
#pragma unroll
    for (int k=0;k<8;k++){
      vf4 v = yp[k];
      xc[4*k]   = fmaxf(0.f, fmaf(v.x, nA[4*k],   nB[4*k]));
      xc[4*k+1] = fmaxf(0.f, fmaf(v.y, nA[4*k+1], nB[4*k+1]));
      xc[4*k+2] = fmaxf(0.f, fmaf(v.z, nA[4*k+2], nB[4*k+2]));
      xc[4*k+3] = fmaxf(0.f, fmaf(v.w, nA[4*k+3], nB[4*k+3]));
    }
  }
#pragma unroll
  for (int gI=0;gI<4;gI++)
#pragma unroll
    for (int o=0;o<MG;o++){
      float sk=0.f;
#pragma unroll
      for (int i=0;i<MG;i++) sk = fmaf(kw[gI*64+o*8+i], xc[gI*MG+i], sk);
      k1[gI*MG+o]=sk;
    }
#pragma unroll
  for (int gI=0;gI<4;gI++)
#pragma unroll
    for (int o=0;o<MG;o++){
      float s=0.f;
#pragma unroll
      for (int i=0;i<16;i++){
        float inp = (gI<2) ? k1[gI*16+i] : xc[(gI-2)*16+i];
        s = fmaf(a1w[gI*128+o*16+i], inp, s);
      }
      at[gI*MG+o]=s;
    }
#pragma unroll
  for (int c=0;c<CM;c++)
    at[c] = fmaxf(0.f, fmaf(at[c], tA[c], tB[c]));
#pragma unroll
  for (int gI=0;gI<4;gI++)
#pragma unroll
    for (int o=0;o<MG;o++){
      float s=0.f;
#pragma unroll
      for (int i=0;i<MG;i++) s = fmaf(a2w[gI*64+o*8+i], at[gI*8+i], s);
      l[gI*MG+o]=s;
    }
#pragma unroll
  for (int gI=0;gI<4;gI++)
#pragma unroll
    for (int o=0;o<MG;o++){
      float sv=0.f;
#pragma unroll
      for (int i=0;i<MG;i++) sv = fmaf(vw[gI*64+o*8+i], xc[gI*MG+i], sv);
      int c = gI*MG+o;
      float lgv = l[c];
      float sm = __expf(lgv*COT_ITAU) * (16384.f/es[b*CM+c]);
      float sg = 1.f/(1.f+__expf(-lgv));
      float mix = (1.f-LAM)*sg + LAM*sm;
      t[c] = fmaf(mix, sv, k1[c]);
    }
  float co[CM];
#pragma unroll
  for (int c=0;c<CM;c++){
    float wl = al*ah[(b*CM+c)*HH + h] + be*awp[(b*CM+c)*WW + w];
    co[c] = xc[c] * wl;   // kappa = 1
  }
  float cot[CM];
#pragma unroll
  for (int o=0;o<CM;o++){
    float s=0.f;
#pragma unroll
    for (int i=0;i<CM;i++) s = fmaf(fw[o*CM+i], t[i], s);
    cot[o]=s;
  }
  float fus[CM];
  float ms=0.f, mq=0.f;
#pragma unroll
  for (int o=0;o<CM;o++){
    float s=0.f;
#pragma unroll
    for (int i=0;i<CM;i++) s = fmaf(fuw[o*64+i], co[i], s);
#pragma unroll
    for (int i=0;i<CM;i++) s = fmaf(fuw[o*64+32+i], cot[i], s);
    fus[o]=s;
    float ss = wsum(s); float qq = wsum(s*s);
    if ((tid&63)==o){ ms=ss; mq=qq; }
  }
  int lane=tid&63;
  if (lane<CM){ atomicAdd(&s1[b*CM+lane],ms); atomicAdd(&s2[b*CM+lane],mq); }
  {
    vf4* fp = (vf4*)(F2 + ((size_t)b*HWSZ + p)*CM);
#pragma unroll
    for (int k=0;k<8;k++){
      vf4 v; v.x=fus[4*k]; v.y=fus[4*k+1]; v.z=fus[4*k+2]; v.w=fus[4*k+3];
      fp[k] = v;
    }
  }
}

// gate statistic: gw-weighted sum of relu(norm(F)) -> one scalar per batch
__global__ __launch_bounds__(256) void k_gstat(const float* __restrict__ F2,
  const float* __restrict__ s1f, const float* __restrict__ s2f,
  const float* __restrict__ fg, const float* __restrict__ fb,
  const float* __restrict__ gw, float* __restrict__ gsum)
{
  __shared__ float fA[CM], fB2[CM], gwl[CM];
  int tid=threadIdx.x;
  int blk=blockIdx.x;
  int b = blk >> 6;
  int p = ((blk&63)<<8)+tid;
  if (tid<CM){
    float mu  = s1f[b*CM+tid]*(1.f/HWSZ);
    float var = fmaf(-mu,mu, s2f[b*CM+tid]*(1.f/HWSZ));
    float a   = rsqrtf(var+EPSF)*fg[tid];
    fA[tid]=a; fB2[tid]=fb[tid]-mu*a;
    gwl[tid]=gw[tid];
  }
  __syncthreads();
  const vf4* fp = (const vf4*)(F2 + ((size_t)b*HWSZ + p)*CM);
  float s=0.f;
#pragma unroll
  for (int k=0;k<8;k++){
    vf4 v = fp[k];
    s = fmaf(gwl[4*k],   fmaxf(0.f, fmaf(v.x, fA[4*k],   fB2[4*k])),   s);
    s = fmaf(gwl[4*k+1], fmaxf(0.f, fmaf(v.y, fA[4*k+1], fB2[4*k+1])), s);
    s = fmaf(gwl[4*k+2], fmaxf(0.f, fmaf(v.z, fA[4*k+2], fB2[4*k+2])), s);
    s = fmaf(gwl[4*k+3], fmaxf(0.f, fmaf(v.w, fA[4*k+3], fB2[4*k+3])), s);
  }
  s = wsum(s);
  if ((tid&63)==0) atomicAdd(&gsum[b], s);
}

// expand conv 32->512 via bf16 MFMA; F read position-major
__global__ __launch_bounds__(256) void k_expand_mfma(
  const float* __restrict__ F2,
  const float* __restrict__ s1f, const float* __restrict__ s2f,
  const float* __restrict__ fg, const float* __restrict__ fb,
  const float* __restrict__ gsum,
  const unsigned short* __restrict__ ewB, float* __restrict__ out)
{
  __shared__ float outT[128][68];
  unsigned short (*fBt)[64][8] = (unsigned short(*)[64][8])&outT[0][0];
  __shared__ float fA[CM], fB2[CM];
  int tid  = threadIdx.x;
  int lane = tid & 63;
  int wv   = tid >> 6;
  int pt   = blockIdx.x;
  int b    = blockIdx.y;
  int z    = blockIdx.z;
  int p0   = pt*64;

  if (tid<CM){
    float mu  = s1f[b*CM+tid]*(1.f/HWSZ);
    float var = fmaf(-mu,mu, s2f[b*CM+tid]*(1.f/HWSZ));
    float a   = rsqrtf(var+EPSF)*fg[tid];
    fA[tid]=a; fB2[tid]=fb[tid]-mu*a;
  }
  float gs = gsum[b]*(1.0f/HWSZ);
  float sc = (1.f/(1.f+__expf(-gs)))*(1.f-GFLOOR)+GFLOOR;
  __syncthreads();

  {
    int pl = tid & 63;
    int g  = tid >> 6;
    const vf4* Fp = (const vf4*)(F2 + ((size_t)b*HWSZ + p0 + pl)*CM + g*8);
    vf4 v0 = Fp[0], v1 = Fp[1];
    float vv[8] = {v0.x,v0.y,v0.z,v0.w,v1.x,v1.y,v1.z,v1.w};
#pragma unroll
    for (int j=0;j<8;j++){
      int k = g*8+j;
      float val = fmaxf(0.f, fmaf(vv[j], fA[k], fB2[k]))*sc;
      fBt[pl>>4][g*16 + (pl&15)][j] = bfc(val);
    }
  }
  __syncthreads();

  int m0 = z*128 + wv*32;
  bf16x8 a0 = *((const bf16x8*)(ewB + (size_t)(m0      + (lane&15))*CM + (lane>>4)*8));
  bf16x8 a1 = *((const bf16x8*)(ewB + (size_t)(m0 + 16 + (lane&15))*CM + (lane>>4)*8));
  f32x4 acc[2][4];
#pragma unroll
  for (int mt=0;mt<2;mt++)
#pragma unroll
    for (int t=0;t<4;t++) acc[mt][t] = (f32x4)(0.f);
#pragma unroll
  for (int t=0;t<4;t++){
    bf16x8 bb = *((const bf16x8*)&fBt[t][lane][0]);
    acc[0][t] = __builtin_amdgcn_mfma_f32_16x16x32_bf16(a0, bb, acc[0][t], 0,0,0);
    acc[1][t] = __builtin_amdgcn_mfma_f32_16x16x32_bf16(a1, bb, acc[1][t], 0,0,0);
  }
  __syncthreads();

#pragma unroll
  for (int mt=0;mt<2;mt++)
#pragma unroll
    for (int t=0;t<4;t++)
#pragma unroll
      for (int r=0;r<4;r++)
        outT[wv*32 + mt*16 + (lane>>4)*4 + r][t*16 + (lane&15)] = acc[mt][t][r];
  __syncthreads();

  {
    float* ob = out + ((size_t)(b*CIN + z*128))*HWSZ + p0;
#pragma unroll
    for (int k2=0;k2<8;k2++){
      int s = tid + 256*k2;
      int row = s >> 4, c4 = (s & 15)*4;
      vf4 v = *((vf4*)&outT[row][c4]);
      __builtin_nontemporal_store(v, (vf4*)(ob + (size_t)row*HWSZ + c4));
    }
  }
}

extern "C" void kernel_launch(void* const* d_in, const int* in_sizes, int n_in,
                              void* d_out, int out_size, void* d_ws, size_t ws_size,
                              hipStream_t stream)
{
  const float* x    = (const float*)d_in[0];
  const float* cw   = (const float*)d_in[1];
  const float* incg = (const float*)d_in[2];
  const float* incb = (const float*)d_in[3];
  const float* pjw  = (const float*)d_in[4];
  const float* pjg  = (const float*)d_in[5];
  const float* pjb  = (const float*)d_in[6];
  const float* chw  = (const float*)d_in[7];
  const float* chb  = (const float*)d_in[8];
  const float* cww  = (const float*)d_in[9];
  const float* cwb  = (const float*)d_in[10];
  const float* alpha= (const float*)d_in[11];
  const float* beta = (const float*)d_in[12];
  const float* kw   = (const float*)d_in[13];
  const float* vw   = (const float*)d_in[14];
  const float* a1w  = (const float*)d_in[15];
  const float* ag   = (const float*)d_in[16];
  const float* ab   = (const float*)d_in[17];
  const float* a2w  = (const float*)d_in[18];
  const float* fw   = (const float*)d_in[19];
  const float* fuw  = (const float*)d_in[20];
  const float* fg   = (const float*)d_in[21];
  const float* fb   = (const float*)d_in[22];
  const float* gw   = (const float*)d_in[23];
  const float* ew   = (const float*)d_in[24];
  float* out = (float*)d_out;

  float* ws = (float*)d_ws;
  const size_t BIG = (size_t)NB*CM*HWSZ;  // 16 MiB
  float* y    = ws;            // position-major [b][p][c]
  float* F    = ws +   BIG;    // position-major [b][p][c]
  float* sm   = ws + 2*BIG;
  float* acc   = sm;  sm += 2048;
  float* statS = acc,      *statQ = acc+256;
  float* attS  = acc+512,  *attQ  = acc+768;
  float* esum  = acc+1024;
  float* fusS  = acc+1280, *fusQ  = acc+1536;
  float* gsum  = acc+1792;
  float* hpool = sm;  sm += NB*CM*HH;
  float* wT    = sm;  sm += CM*CIN;
  unsigned short* ewB = (unsigned short*)sm; sm += CM*CIN/2;
  float* wpart = sm;  sm += (size_t)512*CM*WW;
  float* wpool = sm;  sm += NB*CM*WW;
  float* ahB   = sm;  sm += NB*CM*HH;
  float* awB   = sm;  sm += NB*CM*WW;

  hipMemsetAsync(acc, 0, (2048 + NB*CM*HH)*sizeof(float), stream);
  k_tw<<<64,256,0,stream>>>(cw, wT, ew, ewB);
  k_compress<<<256,512,0,stream>>>(x, wT, y, statS, statQ);
  k_poolstat<<<512,256,0,stream>>>(y,statS,statQ,incg,incb,kw,a1w,attS,attQ,hpool,wpart);
  k_wred<<<NB*CM,128,0,stream>>>(wpart, wpool);
  k_cot2<<<512,256,0,stream>>>(y,statS,statQ,incg,incb,attS,attQ,ag,ab,kw,a1w,a2w,
                               hpool,wpool,pjw,pjg,pjb,chw,chb,cww,cwb,esum,ahB,awB);
  k_mix_fuse<<<512,256,0,stream>>>(y,statS,statQ,incg,incb,attS,attQ,ag,ab,kw,vw,a1w,a2w,
                                   ahB,awB,esum,alpha,beta,fw,fuw,F,fusS,fusQ);
  k_gstat<<<512,256,0,stream>>>(F,fusS,fusQ,fg,fb,gw,gsum);
  k_expand_mfma<<<dim3(256,8,4),256,0,stream>>>(F,fusS,fusQ,fg,fb,gsum,ewB,out);
}

// Round 18
// 348.128 us; speedup vs baseline: 1.0741x; 1.0741x over previous
//
#include <hip/hip_runtime.h>
#include <math.h>

#define NB 8
#define CIN 512
#define CM 32
#define MG 8
#define HH 128
#define WW 128
#define HWSZ (HH*WW)
#define EPSF 1e-5f
#define COT_ITAU 1.25f   // 1/0.8
#define LAM 0.7f
#define GFLOOR 0.05f

typedef float vf4 __attribute__((ext_vector_type(4)));
typedef short bf16x8 __attribute__((ext_vector_type(8)));
typedef float f32x4 __attribute__((ext_vector_type(4)));
typedef unsigned int u32x4 __attribute__((ext_vector_type(4)));

__device__ __forceinline__ float wsum(float v){
#pragma unroll
  for (int o = 32; o; o >>= 1) v += __shfl_xor(v, o, 64);
  return v;
}

__device__ __forceinline__ unsigned short bfc(float x){
  unsigned u = __float_as_uint(x);
  return (unsigned short)((u + 0x7FFFu + ((u>>16)&1u)) >> 16);
}

// async 16B global -> LDS
__device__ __forceinline__ void gload16(const float* g, float* l){
  __builtin_amdgcn_global_load_lds(
    (const __attribute__((address_space(1))) void*)g,
    (__attribute__((address_space(3))) void*)l, 16, 0, 0);
}

// pack compress weights into A-fragment order (bf16); bf16-convert expand weights
__global__ void k_tw(const float* __restrict__ cw, unsigned short* __restrict__ wF,
                     const float* __restrict__ ew, unsigned short* __restrict__ ewB){
  int i = blockIdx.x*256 + threadIdx.x;     // 0..16383
  if (i < CM*CIN){
    int j = i & 7, lane = (i>>3)&63, m = (i>>9)&1, t = i>>10;
    int c = m*16 + (lane&15);
    int k = t*32 + ((lane>>4)<<3) + j;
    wF[i]  = bfc(cw[c*CIN + k]);
    ewB[i] = bfc(ew[i]);
  }
}

// compress conv (512->32) via bf16 MFMA, x hi/lo split (x exact, w bf16).
__global__ __launch_bounds__(256) void k_compress(
    const float* __restrict__ x, const unsigned short* __restrict__ wF,
    float* __restrict__ y, float* __restrict__ s1, float* __restrict__ s2)
{
  __shared__ float xl[2][32*128];            // 32 KB double-buffered x tile
  int tid  = threadIdx.x;
  int lane = tid & 63;
  int wv   = tid >> 6;
  int blk  = blockIdx.x;                     // 0..1023
  int b    = blk >> 7;
  int tile0 = (blk & 127) << 7;              // 128 positions
  const float* xb = x + ((size_t)b*CIN)*HWSZ + tile0;

#define STAGE(t, buf)                                                           \
  {                                                                             \
    _Pragma("unroll")                                                           \
    for (int j=0;j<4;j++){                                                      \
      int ch2 = j*8 + wv*2;                                                     \
      gload16(xb + (size_t)((t)*CM + ch2 + (lane>>5))*HWSZ + (lane&31)*4,       \
              &xl[buf][ch2*128]);                                               \
    }                                                                           \
  }

  STAGE(0, 0)
  __syncthreads();

  f32x4 acc[2][2];
#pragma unroll
  for (int m=0;m<2;m++)
#pragma unroll
    for (int nt=0;nt<2;nt++) acc[m][nt] = (f32x4)(0.f);

  for (int t=0; t<16; ++t){
    int cur = t & 1;
    if (t+1 < 16) STAGE(t+1, cur^1)
    bf16x8 a0 = *((const bf16x8*)(wF + ((size_t)(t*2+0)*64 + lane)*8));
    bf16x8 a1 = *((const bf16x8*)(wF + ((size_t)(t*2+1)*64 + lane)*8));
#pragma unroll
    for (int nt=0;nt<2;nt++){
      int col = wv*32 + nt*16 + (lane&15);
      int r0  = (lane>>4)*8;
      u32x4 hw, lw;
#pragma unroll
      for (int wd=0; wd<4; wd++){
        float f0 = xl[cur][(r0+2*wd  )*128 + col];
        float f1 = xl[cur][(r0+2*wd+1)*128 + col];
        unsigned short h0=bfc(f0), h1=bfc(f1);
        float e0 = f0 - __uint_as_float(((unsigned)h0)<<16);
        float e1 = f1 - __uint_as_float(((unsigned)h1)<<16);
        hw[wd] = (unsigned)h0 | (((unsigned)h1)<<16);
        lw[wd] = (unsigned)bfc(e0) | (((unsigned)bfc(e1))<<16);
      }
      bf16x8 bh = __builtin_bit_cast(bf16x8, hw);
      bf16x8 bl = __builtin_bit_cast(bf16x8, lw);
      if (nt==0){
        acc[0][0] = __builtin_amdgcn_mfma_f32_16x16x32_bf16(a0, bh, acc[0][0], 0,0,0);
        acc[0][0] = __builtin_amdgcn_mfma_f32_16x16x32_bf16(a0, bl, acc[0][0], 0,0,0);
        acc[1][0] = __builtin_amdgcn_mfma_f32_16x16x32_bf16(a1, bh, acc[1][0], 0,0,0);
        acc[1][0] = __builtin_amdgcn_mfma_f32_16x16x32_bf16(a1, bl, acc[1][0], 0,0,0);
      } else {
        acc[0][1] = __builtin_amdgcn_mfma_f32_16x16x32_bf16(a0, bh, acc[0][1], 0,0,0);
        acc[0][1] = __builtin_amdgcn_mfma_f32_16x16x32_bf16(a0, bl, acc[0][1], 0,0,0);
        acc[1][1] = __builtin_amdgcn_mfma_f32_16x16x32_bf16(a1, bh, acc[1][1], 0,0,0);
        acc[1][1] = __builtin_amdgcn_mfma_f32_16x16x32_bf16(a1, bl, acc[1][1], 0,0,0);
      }
    }
    __syncthreads();
  }
#undef STAGE

#pragma unroll
  for (int m=0;m<2;m++)
#pragma unroll
    for (int r=0;r<4;r++){
      float s = acc[m][0][r] + acc[m][1][r];
      float q = acc[m][0][r]*acc[m][0][r] + acc[m][1][r]*acc[m][1][r];
#pragma unroll
      for (int o=1;o<16;o<<=1){ s += __shfl_xor(s,o,64); q += __shfl_xor(q,o,64); }
      if ((lane&15)==0){
        int c = m*16 + (lane>>4)*4 + r;
        atomicAdd(&s1[b*CM+c], s);
        atomicAdd(&s2[b*CM+c], q);
      }
    }

  float* yl = &xl[0][0];
#pragma unroll
  for (int m=0;m<2;m++)
#pragma unroll
    for (int nt=0;nt<2;nt++)
#pragma unroll
      for (int r=0;r<4;r++)
        yl[(m*16 + (lane>>4)*4 + r)*128 + wv*32 + nt*16 + (lane&15)] = acc[m][nt][r];
  __syncthreads();
#pragma unroll
  for (int k2=0;k2<4;k2++){
    int s = tid + 256*k2;
    int row = s >> 5, c4s = s & 31;
    ((vf4*)(y + ((size_t)(b*CM+row))*HWSZ + tile0))[c4s] = *((vf4*)&yl[row*128 + c4s*4]);
  }
}

// att_pre stats + BOTH pools in one y-pass (validated).
__global__ __launch_bounds__(256) void k_poolstat(
  const float* __restrict__ y,
  const float* __restrict__ s1i, const float* __restrict__ s2i,
  const float* __restrict__ incg, const float* __restrict__ incb,
  const float* __restrict__ kw, const float* __restrict__ a1w,
  float* __restrict__ s1, float* __restrict__ s2,
  float* __restrict__ hpool, float* __restrict__ wpart)
{
  __shared__ float nA[CM], nB[CM];
  __shared__ float sh[CM][128];
  int tid=threadIdx.x;
  int blk=blockIdx.x;
  int b = blk >> 6;
  int p = ((blk&63)<<8)+tid;
  if (tid<CM){
    float mu  = s1i[b*CM+tid]*(1.f/HWSZ);
    float var = fmaf(-mu,mu, s2i[b*CM+tid]*(1.f/HWSZ));
    float a   = rsqrtf(var+EPSF)*incg[tid];
    nA[tid]=a; nB[tid]=incb[tid]-mu*a;
  }
  __syncthreads();
  size_t base = ((size_t)b*CM)*HWSZ + p;
  float xc[CM], k1[CM], at[CM];
#pragma unroll
  for (int c=0;c<CM;c++)
    xc[c] = fmaxf(0.f, fmaf(y[base+(size_t)c*HWSZ], nA[c], nB[c]));
  if (tid>=128){
#pragma unroll
    for (int c=0;c<CM;c++) sh[c][tid-128]=xc[c];
  }
  __syncthreads();
  if (tid<128){
    float* wp = wpart + (size_t)blk*(CM*WW) + tid;
#pragma unroll
    for (int c=0;c<CM;c++) wp[c*WW] = xc[c] + sh[c][tid];
  }
  {
    int hrow = p >> 7;
    float ms=0.f;
#pragma unroll
    for (int c=0;c<CM;c++){
      float s=wsum(xc[c]);
      if ((tid&63)==c) ms=s;
    }
    int lane=tid&63;
    if (lane<CM) atomicAdd(&hpool[(b*CM+lane)*HH+hrow], ms*(1.f/WW));
  }
#pragma unroll
  for (int gI=0;gI<4;gI++)
#pragma unroll
    for (int o=0;o<MG;o++){
      float sk=0.f;
#pragma unroll
      for (int i=0;i<MG;i++) sk = fmaf(kw[gI*64+o*8+i], xc[gI*MG+i], sk);
      k1[gI*MG+o]=sk;
    }
#pragma unroll
  for (int gI=0;gI<4;gI++)
#pragma unroll
    for (int o=0;o<MG;o++){
      float s=0.f;
#pragma unroll
      for (int i=0;i<16;i++){
        float inp = (gI<2) ? k1[gI*16+i] : xc[(gI-2)*16+i];
        s = fmaf(a1w[gI*128+o*16+i], inp, s);
      }
      at[gI*MG+o]=s;
    }
  float ms=0.f,mq=0.f;
#pragma unroll
  for (int c=0;c<CM;c++){
    float s=wsum(at[c]); float q=wsum(at[c]*at[c]);
    if ((tid&63)==c){ms=s;mq=q;}
  }
  int lane=tid&63;
  if (lane<CM){ atomicAdd(&s1[b*CM+lane],ms); atomicAdd(&s2[b*CM+lane],mq); }
}

// reduce wpart -> wpool
__global__ void k_wred(const float* __restrict__ wpart, float* __restrict__ wpool){
  int bc = blockIdx.x;
  int w  = threadIdx.x;
  int b  = bc >> 5;
  int c  = bc & 31;
  const float* src = wpart + (size_t)(b*64)*(CM*WW) + c*WW + w;
  float s=0.f;
#pragma unroll 8
  for (int k=0;k<64;k++) s += src[(size_t)k*(CM*WW)];
  wpool[bc*WW + w] = s*(1.0f/HH);
}

// softmax denominator; blocks 0..15 also run coord MLP
__global__ __launch_bounds__(256) void k_cot2(
  const float* __restrict__ y,
  const float* __restrict__ s1i, const float* __restrict__ s2i,
  const float* __restrict__ incg, const float* __restrict__ incb,
  const float* __restrict__ s1a, const float* __restrict__ s2a,
  const float* __restrict__ ag, const float* __restrict__ ab,
  const float* __restrict__ kw, const float* __restrict__ a1w, const float* __restrict__ a2w,
  const float* __restrict__ hpool, const float* __restrict__ wpool,
  const float* __restrict__ pjw, const float* __restrict__ pjg, const float* __restrict__ pjb,
  const float* __restrict__ chw, const float* __restrict__ chb,
  const float* __restrict__ cww, const float* __restrict__ cwb,
  float* __restrict__ es, float* __restrict__ ah, float* __restrict__ aw)
{
  __shared__ float T[CM][HH+1];
  __shared__ float sa[CM], sb[CM], smx[CM], ssc[CM];
  __shared__ float nA[CM], nB[CM], tA[CM], tB[CM];
  int tid=threadIdx.x;
  int blk=blockIdx.x;
  int b = blk >> 6;
  int p = ((blk&63)<<8)+tid;
  if (tid<CM){
    float mu  = s1i[b*CM+tid]*(1.f/HWSZ);
    float var = fmaf(-mu,mu, s2i[b*CM+tid]*(1.f/HWSZ));
    float a   = rsqrtf(var+EPSF)*incg[tid];
    nA[tid]=a; nB[tid]=incb[tid]-mu*a;
    float mu2  = s1a[b*CM+tid]*(1.f/HWSZ);
    float var2 = fmaf(-mu2,mu2, s2a[b*CM+tid]*(1.f/HWSZ));
    float a2   = rsqrtf(var2+EPSF)*ag[tid];
    tA[tid]=a2; tB[tid]=ab[tid]-mu2*a2;
  }
  __syncthreads();
  size_t base = ((size_t)b*CM)*HWSZ + p;
  float xc[CM], k1[CM], at[CM], l[CM];
#pragma unroll
  for (int c=0;c<CM;c++)
    xc[c] = fmaxf(0.f, fmaf(y[base+(size_t)c*HWSZ], nA[c], nB[c]));
#pragma unroll
  for (int gI=0;gI<4;gI++)
#pragma unroll
    for (int o=0;o<MG;o++){
      float sk=0.f;
#pragma unroll
      for (int i=0;i<MG;i++) sk = fmaf(kw[gI*64+o*8+i], xc[gI*MG+i], sk);
      k1[gI*MG+o]=sk;
    }
#pragma unroll
  for (int gI=0;gI<4;gI++)
#pragma unroll
    for (int o=0;o<MG;o++){
      float s=0.f;
#pragma unroll
      for (int i=0;i<16;i++){
        float inp = (gI<2) ? k1[gI*16+i] : xc[(gI-2)*16+i];
        s = fmaf(a1w[gI*128+o*16+i], inp, s);
      }
      at[gI*MG+o]=s;
    }
#pragma unroll
  for (int c=0;c<CM;c++)
    at[c] = fmaxf(0.f, fmaf(at[c], tA[c], tB[c]));
#pragma unroll
  for (int gI=0;gI<4;gI++)
#pragma unroll
    for (int o=0;o<MG;o++){
      float s=0.f;
#pragma unroll
      for (int i=0;i<MG;i++) s = fmaf(a2w[gI*64+o*8+i], at[gI*8+i], s);
      l[gI*MG+o]=s;
    }
  float ms=0.f;
#pragma unroll
  for (int c=0;c<CM;c++){
    float s = wsum(__expf(l[c]*COT_ITAU));
    if ((tid&63)==c) ms=s;
  }
  int lane=tid&63;
  if (lane<CM) atomicAdd(&es[b*CM+lane], ms);

  if (blk < 2*NB){
    int bb = blk>>1, path = blk&1;
    const float* pool = path ? wpool : hpool;
    const float* w2   = path ? cww : chw;
    const float* b2   = path ? cwb : chb;
    float* outp       = path ? aw  : ah;
    float z[CM];
    if (tid<HH){
      float in[CM];
#pragma unroll
      for (int c=0;c<CM;c++) in[c] = pool[(bb*CM+c)*HH + tid];
#pragma unroll
      for (int gI=0;gI<4;gI++)
#pragma unroll
        for (int o=0;o<MG;o++){
          float s=0.f;
#pragma unroll
          for (int i=0;i<MG;i++) s = fmaf(pjw[gI*64+o*8+i], in[gI*8+i], s);
          T[gI*8+o][tid] = s;
        }
    }
    __syncthreads();
    if (tid < CM){
      float s=0.f, q=0.f;
      for (int k=0;k<HH;k++){ float t=T[tid][k]; s+=t; q+=t*t; }
      float mu = s*(1.0f/HH);
      float var = q*(1.0f/HH) - mu*mu;
      float a = rsqrtf(var+EPSF)*pjg[tid];
      sa[tid]=a; sb[tid]=pjb[tid]-mu*a;
    }
    __syncthreads();
    if (tid<HH){
      float sil[CM];
#pragma unroll
      for (int c=0;c<CM;c++){
        float val = fmaf(T[c][tid], sa[c], sb[c]);
        sil[c] = val/(1.f+__expf(-val));
      }
#pragma unroll
      for (int gI=0;gI<4;gI++)
#pragma unroll
        for (int o=0;o<MG;o++){
          float s=b2[gI*8+o];
#pragma unroll
          for (int i=0;i<MG;i++) s = fmaf(w2[gI*64+o*8+i], sil[gI*8+i], s);
          z[gI*8+o]=s;
        }
    }
    __syncthreads();
    if (tid<HH){
#pragma unroll
      for (int c=0;c<CM;c++) T[c][tid]=z[c];
    }
    __syncthreads();
    if (tid < CM){
      float mx=-1e30f;
      for (int k=0;k<HH;k++) mx = fmaxf(mx, T[tid][k]);
      float s=0.f;
      for (int k=0;k<HH;k++) s += __expf(T[tid][k]-mx);
      smx[tid]=mx; ssc[tid]=(float)HH/s;
    }
    __syncthreads();
    if (tid<HH){
#pragma unroll
      for (int c=0;c<CM;c++)
        outp[(bb*CM+c)*HH + tid] = __expf(T[c][tid]-smx[c])*ssc[c];
    }
  }
}

// mix + cot_fuse + coord combine + fusion (+ fus stats)
__global__ __launch_bounds__(256) void k_mix_fuse(
  const float* __restrict__ y,
  const float* __restrict__ s1i, const float* __restrict__ s2i,
  const float* __restrict__ incg, const float* __restrict__ incb,
  const float* __restrict__ s1a, const float* __restrict__ s2a,
  const float* __restrict__ ag, const float* __restrict__ ab,
  const float* __restrict__ kw, const float* __restrict__ vw,
  const float* __restrict__ a1w, const float* __restrict__ a2w,
  const float* __restrict__ ah, const float* __restrict__ awp, const float* __restrict__ es,
  const float* __restrict__ alpha, const float* __restrict__ beta,
  const float* __restrict__ fw, const float* __restrict__ fuw,
  float* __restrict__ fpo, float* __restrict__ s1, float* __restrict__ s2)
{
  __shared__ float nA[CM], nB[CM], tA[CM], tB[CM];
  int tid=threadIdx.x;
  int b = blockIdx.x>>6;
  int p = ((blockIdx.x&63)<<8)+tid;
  int h = p >> 7, w = p & (WW-1);
  if (tid<CM){
    float mu  = s1i[b*CM+tid]*(1.f/HWSZ);
    float var = fmaf(-mu,mu, s2i[b*CM+tid]*(1.f/HWSZ));
    float a   = rsqrtf(var+EPSF)*incg[tid];
    nA[tid]=a; nB[tid]=incb[tid]-mu*a;
    float mu2  = s1a[b*CM+tid]*(1.f/HWSZ);
    float var2 = fmaf(-mu2,mu2, s2a[b*CM+tid]*(1.f/HWSZ));
    float a2   = rsqrtf(var2+EPSF)*ag[tid];
    tA[tid]=a2; tB[tid]=ab[tid]-mu2*a2;
  }
  __syncthreads();
  size_t base = ((size_t)b*CM)*HWSZ + p;
  float al=alpha[0], be=beta[0];
  float xc[CM], k1[CM], at[CM], l[CM], t[CM];
#pragma unroll
  for (int c=0;c<CM;c++)
    xc[c] = fmaxf(0.f, fmaf(y[base+(size_t)c*HWSZ], nA[c], nB[c]));
#pragma unroll
  for (int gI=0;gI<4;gI++)
#pragma unroll
    for (int o=0;o<MG;o++){
      float sk=0.f;
#pragma unroll
      for (int i=0;i<MG;i++) sk = fmaf(kw[gI*64+o*8+i], xc[gI*MG+i], sk);
      k1[gI*MG+o]=sk;
    }
#pragma unroll
  for (int gI=0;gI<4;gI++)
#pragma unroll
    for (int o=0;o<MG;o++){
      float s=0.f;
#pragma unroll
      for (int i=0;i<16;i++){
        float inp = (gI<2) ? k1[gI*16+i] : xc[(gI-2)*16+i];
        s = fmaf(a1w[gI*128+o*16+i], inp, s);
      }
      at[gI*MG+o]=s;
    }
#pragma unroll
  for (int c=0;c<CM;c++)
    at[c] = fmaxf(0.f, fmaf(at[c], tA[c], tB[c]));
#pragma unroll
  for (int gI=0;gI<4;gI++)
#pragma unroll
    for (int o=0;o<MG;o++){
      float s=0.f;
#pragma unroll
      for (int i=0;i<MG;i++) s = fmaf(a2w[gI*64+o*8+i], at[gI*8+i], s);
      l[gI*MG+o]=s;
    }
#pragma unroll
  for (int gI=0;gI<4;gI++)
#pragma unroll
    for (int o=0;o<MG;o++){
      float sv=0.f;
#pragma unroll
      for (int i=0;i<MG;i++) sv = fmaf(vw[gI*64+o*8+i], xc[gI*MG+i], sv);
      int c = gI*MG+o;
      float lgv = l[c];
      float sm = __expf(lgv*COT_ITAU) * (16384.f/es[b*CM+c]);
      float sg = 1.f/(1.f+__expf(-lgv));
      float mix = (1.f-LAM)*sg + LAM*sm;
      t[c] = fmaf(mix, sv, k1[c]);
    }
  float co[CM];
#pragma unroll
  for (int c=0;c<CM;c++){
    float wl = al*ah[(b*CM+c)*HH + h] + be*awp[(b*CM+c)*WW + w];
    co[c] = xc[c] * wl;   // kappa = 1
  }
  float cot[CM];
#pragma unroll
  for (int o=0;o<CM;o++){
    float s=0.f;
#pragma unroll
    for (int i=0;i<CM;i++) s = fmaf(fw[o*CM+i], t[i], s);
    cot[o]=s;
  }
  float ms=0.f, mq=0.f;
#pragma unroll
  for (int o=0;o<CM;o++){
    float s=0.f;
#pragma unroll
    for (int i=0;i<CM;i++) s = fmaf(fuw[o*64+i], co[i], s);
#pragma unroll
    for (int i=0;i<CM;i++) s = fmaf(fuw[o*64+32+i], cot[i], s);
    fpo[base+(size_t)o*HWSZ]=s;
    float ss = wsum(s); float qq = wsum(s*s);
    if ((tid&63)==o){ ms=ss; mq=qq; }
  }
  int lane=tid&63;
  if (lane<CM){ atomicAdd(&s1[b*CM+lane],ms); atomicAdd(&s2[b*CM+lane],mq); }
}

// gate statistics
__global__ __launch_bounds__(256) void k_gstat(const float4* __restrict__ fp,
  const float* __restrict__ s1f, const float* __restrict__ s2f,
  const float* __restrict__ fg, const float* __restrict__ fb,
  float* __restrict__ gsum)
{
  int idx = blockIdx.x*256+threadIdx.x;
  int bc = idx >> 12;
  int c = bc & (CM-1);
  float mu  = s1f[bc]*(1.f/HWSZ);
  float var = fmaf(-mu,mu, s2f[bc]*(1.f/HWSZ));
  float a   = rsqrtf(var+EPSF)*fg[c];
  float bb  = fb[c]-mu*a;
  float4 tv = fp[idx];
  float s = fmaxf(0.f,fmaf(tv.x,a,bb))+fmaxf(0.f,fmaf(tv.y,a,bb))
          + fmaxf(0.f,fmaf(tv.z,a,bb))+fmaxf(0.f,fmaf(tv.w,a,bb));
  s = wsum(s);
  if ((threadIdx.x&63)==0) atomicAdd(&gsum[bc], s);
}

// expand conv 32->512 via bf16 MFMA (r14-validated)
__global__ __launch_bounds__(256) void k_expand_mfma(
  const float* __restrict__ F,
  const float* __restrict__ s1f, const float* __restrict__ s2f,
  const float* __restrict__ fg, const float* __restrict__ fb,
  const float* __restrict__ gw, const float* __restrict__ gsum,
  const unsigned short* __restrict__ ewB, float* __restrict__ out)
{
  __shared__ float outT[128][68];
  unsigned short (*fBt)[64][8] = (unsigned short(*)[64][8])&outT[0][0];
  __shared__ float fA[CM], fB2[CM];
  int tid  = threadIdx.x;
  int lane = tid & 63;
  int wv   = tid >> 6;
  int pt   = blockIdx.x;
  int b    = blockIdx.y;
  int z    = blockIdx.z;
  int p0   = pt*64;

  if (tid<CM){
    float mu  = s1f[b*CM+tid]*(1.f/HWSZ);
    float var = fmaf(-mu,mu, s2f[b*CM+tid]*(1.f/HWSZ));
    float a   = rsqrtf(var+EPSF)*fg[tid];
    fA[tid]=a; fB2[tid]=fb[tid]-mu*a;
  }
  float gs=0.f;
#pragma unroll
  for (int c=0;c<CM;c++) gs = fmaf(gw[c], gsum[b*CM+c], gs);
  gs *= (1.0f/HWSZ);
  float sc = (1.f/(1.f+__expf(-gs)))*(1.f-GFLOOR)+GFLOOR;
  __syncthreads();

  {
    int k  = tid >> 3;
    int pb = (tid & 7) * 8;
    const float* Fb = F + ((size_t)(b*CM + k))*HWSZ + p0 + pb;
    float a = fA[k], bb = fB2[k];
    int ls_hi = (k>>3)*16;
    int j = k & 7;
#pragma unroll
    for (int u=0;u<8;u++){
      int p = pb + u;
      float v = fmaxf(0.f, fmaf(Fb[u], a, bb))*sc;
      fBt[p>>4][ls_hi + (p&15)][j] = bfc(v);
    }
  }
  __syncthreads();

  int m0 = z*128 + wv*32;
  bf16x8 a0 = *((const bf16x8*)(ewB + (size_t)(m0      + (lane&15))*CM + (lane>>4)*8));
  bf16x8 a1 = *((const bf16x8*)(ewB + (size_t)(m0 + 16 + (lane&15))*CM + (lane>>4)*8));
  f32x4 acc[2][4];
#pragma unroll
  for (int mt=0;mt<2;mt++)
#pragma unroll
    for (int t=0;t<4;t++) acc[mt][t] = (f32x4)(0.f);
#pragma unroll
  for (int t=0;t<4;t++){
    bf16x8 bb = *((const bf16x8*)&fBt[t][lane][0]);
    acc[0][t] = __builtin_amdgcn_mfma_f32_16x16x32_bf16(a0, bb, acc[0][t], 0,0,0);
    acc[1][t] = __builtin_amdgcn_mfma_f32_16x16x32_bf16(a1, bb, acc[1][t], 0,0,0);
  }
  __syncthreads();

#pragma unroll
  for (int mt=0;mt<2;mt++)
#pragma unroll
    for (int t=0;t<4;t++)
#pragma unroll
      for (int r=0;r<4;r++)
        outT[wv*32 + mt*16 + (lane>>4)*4 + r][t*16 + (lane&15)] = acc[mt][t][r];
  __syncthreads();

  {
    float* ob = out + ((size_t)(b*CIN + z*128))*HWSZ + p0;
#pragma unroll
    for (int k2=0;k2<8;k2++){
      int s = tid + 256*k2;
      int row = s >> 4, c4 = (s & 15)*4;
      vf4 v = *((vf4*)&outT[row][c4]);
      __builtin_nontemporal_store(v, (vf4*)(ob + (size_t)row*HWSZ + c4));
    }
  }
}

extern "C" void kernel_launch(void* const* d_in, const int* in_sizes, int n_in,
                              void* d_out, int out_size, void* d_ws, size_t ws_size,
                              hipStream_t stream)
{
  const float* x    = (const float*)d_in[0];
  const float* cw   = (const float*)d_in[1];
  const float* incg = (const float*)d_in[2];
  const float* incb = (const float*)d_in[3];
  const float* pjw  = (const float*)d_in[4];
  const float* pjg  = (const float*)d_in[5];
  const float* pjb  = (const float*)d_in[6];
  const float* chw  = (const float*)d_in[7];
  const float* chb  = (const float*)d_in[8];
  const float* cww  = (const float*)d_in[9];
  const float* cwb  = (const float*)d_in[10];
  const float* alpha= (const float*)d_in[11];
  const float* beta = (const float*)d_in[12];
  const float* kw   = (const float*)d_in[13];
  const float* vw   = (const float*)d_in[14];
  const float* a1w  = (const float*)d_in[15];
  const float* ag   = (const float*)d_in[16];
  const float* ab   = (const float*)d_in[17];
  const float* a2w  = (const float*)d_in[18];
  const float* fw   = (const float*)d_in[19];
  const float* fuw  = (const float*)d_in[20];
  const float* fg   = (const float*)d_in[21];
  const float* fb   = (const float*)d_in[22];
  const float* gw   = (const float*)d_in[23];
  const float* ew   = (const float*)d_in[24];
  float* out = (float*)d_out;

  float* ws = (float*)d_ws;
  const size_t BIG = (size_t)NB*CM*HWSZ;  // 16 MiB
  float* y    = ws;
  float* F    = ws +   BIG;
  float* sm   = ws + 2*BIG;
  float* acc   = sm;  sm += 2048;
  float* statS = acc,      *statQ = acc+256;
  float* attS  = acc+512,  *attQ  = acc+768;
  float* esum  = acc+1024;
  float* fusS  = acc+1280, *fusQ  = acc+1536;
  float* gsum  = acc+1792;
  float* hpool = sm;  sm += NB*CM*HH;
  unsigned short* wF  = (unsigned short*)sm; sm += CM*CIN/2;  // bf16 A-frags
  unsigned short* ewB = (unsigned short*)sm; sm += CM*CIN/2;
  float* wpart = sm;  sm += (size_t)512*CM*WW;
  float* wpool = sm;  sm += NB*CM*WW;
  float* ahB   = sm;  sm += NB*CM*HH;
  float* awB   = sm;  sm += NB*CM*WW;

  hipMemsetAsync(acc, 0, (2048 + NB*CM*HH)*sizeof(float), stream);
  k_tw<<<64,256,0,stream>>>(cw, wF, ew, ewB);
  k_compress<<<1024,256,0,stream>>>(x, wF, y, statS, statQ);
  k_poolstat<<<512,256,0,stream>>>(y,statS,statQ,incg,incb,kw,a1w,attS,attQ,hpool,wpart);
  k_wred<<<NB*CM,128,0,stream>>>(wpart, wpool);
  k_cot2<<<512,256,0,stream>>>(y,statS,statQ,incg,incb,attS,attQ,ag,ab,kw,a1w,a2w,
                               hpool,wpool,pjw,pjg,pjb,chw,chb,cww,cwb,esum,ahB,awB);
  k_mix_fuse<<<512,256,0,stream>>>(y,statS,statQ,incg,incb,attS,attQ,ag,ab,kw,vw,a1w,a2w,
                                   ahB,awB,esum,alpha,beta,fw,fuw,F,fusS,fusQ);
  k_gstat<<<4096,256,0,stream>>>((const float4*)F,fusS,fusQ,fg,fb,gsum);
  k_expand_mfma<<<dim3(256,8,4),256,0,stream>>>(F,fusS,fusQ,fg,fb,gw,gsum,ewB,out);
}